// Round 4
// baseline (102.869 us; speedup 1.0000x reference)
//
#include <hip/hip_runtime.h>

#define BB 8
#define TT 256
#define UU 64
#define VV 512
#define U1 (UU + 1)

#define LOG2E 1.4426950408889634f
#define LN2   0.6931471805599453f
#define NEG_INF (-__builtin_inff())

typedef float floatx4 __attribute__((ext_vector_type(4)));

__device__ __forceinline__ float vexp2(float x) {
    float r; asm("v_exp_f32 %0, %1" : "=v"(r) : "v"(x)); return r;
}
__device__ __forceinline__ float vlog2(float x) {
    float r; asm("v_log_f32 %0, %1" : "=v"(r) : "v"(x)); return r;
}

template<int CTRL, int RMASK>
__device__ __forceinline__ float dpp_mov(float v, float oldv) {
    int r = __builtin_amdgcn_update_dpp(__float_as_int(oldv), __float_as_int(v),
                                        CTRL, RMASK, 0xf, false);
    return __int_as_float(r);
}

// wave64 inclusive add-scan via DPP (identity = 0)
__device__ __forceinline__ float wave_addscan(float v) {
    v += dpp_mov<0x111, 0xf>(v, 0.f);
    v += dpp_mov<0x112, 0xf>(v, 0.f);
    v += dpp_mov<0x114, 0xf>(v, 0.f);
    v += dpp_mov<0x118, 0xf>(v, 0.f);
    v += dpp_mov<0x142, 0xa>(v, 0.f);
    v += dpp_mov<0x143, 0xc>(v, 0.f);
    return v;
}

// Kernel 1: per-row log-softmax; extract blank lp and target (emit) lp.
__global__ __launch_bounds__(256) void k_logsm(const float* __restrict__ logits,
                                               const int* __restrict__ targets,
                                               float* __restrict__ blank,
                                               float* __restrict__ emit) {
    int wave = (int)((blockIdx.x * blockDim.x + threadIdx.x) >> 6);
    int lane = threadIdx.x & 63;
    const int nrows = BB * TT * U1;
    if (wave >= nrows) return;
    const float* row = logits + (size_t)wave * VV;
    floatx4 v0 = __builtin_nontemporal_load((const floatx4*)(row + lane * 4));
    floatx4 v1 = __builtin_nontemporal_load((const floatx4*)(row + 256 + lane * 4));
    float m = fmaxf(fmaxf(fmaxf(v0.x, v0.y), fmaxf(v0.z, v0.w)),
                    fmaxf(fmaxf(v1.x, v1.y), fmaxf(v1.z, v1.w)));
    #pragma unroll
    for (int off = 32; off; off >>= 1) m = fmaxf(m, __shfl_xor(m, off));
    float s = __expf(v0.x - m) + __expf(v0.y - m) + __expf(v0.z - m) + __expf(v0.w - m)
            + __expf(v1.x - m) + __expf(v1.y - m) + __expf(v1.z - m) + __expf(v1.w - m);
    #pragma unroll
    for (int off = 32; off; off >>= 1) s += __shfl_xor(s, off);
    float lse = m + __logf(s);

    int u  = wave % U1;
    int bt = wave / U1;
    if (lane == 0) blank[wave] = v0.x - lse;
    if (u < UU) {
        int b = bt / TT;
        int tgt = targets[b * UU + u];           // in [1, V)
        int owner = (tgt & 255) >> 2;
        if (lane == owner) {
            int slot = tgt & 3;
            float x0 = (tgt < 256) ? v0.x : v1.x;
            float x1 = (tgt < 256) ? v0.y : v1.y;
            float x2 = (tgt < 256) ? v0.z : v1.z;
            float x3 = (tgt < 256) ? v0.w : v1.w;
            float val = (slot == 0) ? x0 : (slot == 1) ? x1 : (slot == 2) ? x2 : x3;
            emit[bt * UU + u] = val - lse;
        }
    }
}

// Kernel 2: build cum (exclusive, nat log) and D/z64 (log2 domain) for the scan.
// Lane l <-> u = l. D[b][s][l] = LOG2E*(blank[b][s][l] + cumx[b][s][l] - cumx[b][s+1][l])
// (cumx = exclusive prefix of emit); z64[b][s] = same at u=64 (inclusive totals).
// D stored grouped: Dg[((b*64 + (s>>2))*64 + l)*4 + (s&3)] for float4 loads in k_scan.
__global__ __launch_bounds__(256) void k_prep(const float* __restrict__ emit,
                                              const float* __restrict__ blank,
                                              float* __restrict__ cum,
                                              float* __restrict__ Dg,
                                              float* __restrict__ z64,
                                              float* __restrict__ out0) {
    int wave = (int)((blockIdx.x * blockDim.x + threadIdx.x) >> 6);
    int l = threadIdx.x & 63;
    if (wave >= BB * TT) return;
    if (wave == 0 && l == 0) out0[0] = 0.f;   // zero output for k_scan's atomicAdd
    int b = wave >> 8, t = wave & 255;
    float e = emit[wave * UU + l];
    float incl = wave_addscan(e);
    float excl = incl - e;                    // exact 0 at lane 0
    cum[wave * U1 + l] = excl;
    float inclT63 = __shfl(incl, 63);
    if (l == 63) cum[wave * U1 + 64] = incl;
    if (t >= 1) {
        float eP = emit[(wave - 1) * UU + l];
        float inclP = wave_addscan(eP);
        float exclP = inclP - eP;
        float bl = blank[(size_t)(wave - 1) * U1 + l];
        int s = t - 1;
        Dg[((b * 64 + (s >> 2)) * 64 + l) * 4 + (s & 3)] = (bl + exclP - excl) * LOG2E;
        float inclP63 = __shfl(inclP, 63);
        if (l == 0)
            z64[wave - 1] = (blank[(size_t)(wave - 1) * U1 + 64] + inclP63 - inclT63) * LOG2E;
    } else {
        Dg[((b * 64 + 63) * 64 + l) * 4 + 3] = 0.f;   // pad step s=255
        if (l == 0) z64[b * 256 + 255] = 0.f;
    }
}

// Kernel 3: per-batch alpha recursion. State carried as (m,s) pairs: value = m + log2(s).
// Critical path per scan stage = dpp+fmax only; sum chain lags constant behind.
__global__ __launch_bounds__(64) void k_scan(const float* __restrict__ Dg,
                                             const float* __restrict__ z64,
                                             const float* __restrict__ cum,
                                             const float* __restrict__ blank,
                                             const int* __restrict__ loglen,
                                             const int* __restrict__ tgtlen,
                                             float* __restrict__ out) {
    int b = blockIdx.x;
    int l = threadIdx.x;                  // owns u = l (0..63); u=64 side-chain in lane 63
    int t_idx = loglen[b] - 1;
    int u_idx = tgtlen[b];
    int t_sel = t_idx - 1;
    const float* Db = Dg + (size_t)b * 64 * 64 * 4;
    const float* zb = z64 + b * 256;

    float am = 0.f, as = 1.f;             // g pair, g = am + log2(as); init g=0
    float a64m = 0.f, a64s = 1.f;         // u=64 pair
    float gm = 0.f, gs = 1.f;             // recorded pair

    float rA[4], zA[4], rB[4], zB[4], rC[4], zC[4];

#define LOADG(r_, z_, c_) do { int c__ = (c_);                                   \
        if (c__ < 64) {                                                          \
            *(float4*)(r_) = *(const float4*)(Db + (c__ * 64 + l) * 4);          \
            *(float4*)(z_) = *(const float4*)(zb + 4 * c__);                     \
        } } while (0)

#define SCAN_STAGE(CTRL, RM)                                    \
    {   float pm = dpp_mov<CTRL, RM>(fm, NEG_INF);              \
        float ps = dpp_mov<CTRL, RM>(fs, 0.f);                  \
        float M  = fmaxf(fm, pm);                               \
        float ea = vexp2(fm - M);                               \
        float eb = vexp2(pm - M);                               \
        fs = fs * ea + ps * eb;                                 \
        fm = M; }

#define STEP4(r_, z_, c_) do { int cbase = 4 * (c_);                             \
        _Pragma("unroll")                                                        \
        for (int i = 0; i < 4; ++i) {                                            \
            float fm = am + r_[i];                                               \
            float fs = as;                                                       \
            SCAN_STAGE(0x111, 0xf)                                               \
            SCAN_STAGE(0x112, 0xf)                                               \
            SCAN_STAGE(0x114, 0xf)                                               \
            SCAN_STAGE(0x118, 0xf)                                               \
            SCAN_STAGE(0x142, 0xa)                                               \
            SCAN_STAGE(0x143, 0xc)                                               \
            float f64m = a64m + z_[i];                                           \
            float f64s = a64s;                                                   \
            {   float M  = fmaxf(f64m, fm);                                      \
                float ea = vexp2(f64m - M);                                      \
                float eb = vexp2(fm - M);                                        \
                f64s = f64s * ea + fs * eb;                                      \
                f64m = M; }                                                      \
            int s = cbase + i;               /* step computes alpha at t=s+1 */  \
            if (s == t_sel) {                                                    \
                if (l == u_idx) { gm = fm; gs = fs; }                            \
                if (u_idx == 64 && l == 63) { gm = f64m; gs = f64s; }            \
            }                                                                    \
            am = fm; as = fs; a64m = f64m; a64s = f64s;                          \
        }                                                                        \
        { int e1; as = frexpf(as, &e1); am += (float)e1;                         \
          int e2; a64s = frexpf(a64s, &e2); a64m += (float)e2; }                 \
    } while (0)

    LOADG(rA, zA, 0);
    LOADG(rB, zB, 1);
    LOADG(rC, zC, 2);

    for (int cc = 0; cc < 21; ++cc) {
        STEP4(rA, zA, 3 * cc + 0);  LOADG(rA, zA, 3 * cc + 3);
        STEP4(rB, zB, 3 * cc + 1);  LOADG(rB, zB, 3 * cc + 4);
        STEP4(rC, zC, 3 * cc + 2);  LOADG(rC, zC, 3 * cc + 5);
    }
    STEP4(rA, zA, 63);

    int writer_lane = (u_idx < 64) ? u_idx : 63;
    if (l == writer_lane) {
        float g = (gm + vlog2(gs)) * LN2;
        size_t idx = ((size_t)b * 256 + t_idx) * U1 + u_idx;
        float a  = cum[idx] + g;
        float fb = blank[idx];
        atomicAdd(out, -0.125f * (a + fb));
    }
#undef LOADG
#undef SCAN_STAGE
#undef STEP4
}

extern "C" void kernel_launch(void* const* d_in, const int* in_sizes, int n_in,
                              void* d_out, int out_size, void* d_ws, size_t ws_size,
                              hipStream_t stream) {
    const float* logits  = (const float*)d_in[0];
    const int*   targets = (const int*)d_in[1];
    const int*   loglen  = (const int*)d_in[2];
    const int*   tgtlen  = (const int*)d_in[3];

    float* ws    = (float*)d_ws;
    float* blank = ws;                         // B*T*(U+1) = 133120
    float* emit  = blank + BB * TT * U1;       // B*T*U     = 131072
    float* cum   = emit  + BB * TT * UU;       // B*T*(U+1) = 133120
    float* Dg    = cum   + BB * TT * U1;       // 8*64*64*4 = 131072
    float* z64   = Dg    + BB * 64 * 64 * 4;   // B*256     = 2048

    const int nrows = BB * TT * U1;
    k_logsm<<<nrows / 4, 256, 0, stream>>>(logits, targets, blank, emit);
    k_prep<<<(BB * TT) / 4, 256, 0, stream>>>(emit, blank, cum, Dg, z64, (float*)d_out);
    k_scan<<<BB, 64, 0, stream>>>(Dg, z64, cum, blank, loglen, tgtlen, (float*)d_out);
}